// Round 4
// baseline (289.143 us; speedup 1.0000x reference)
//
#include <hip/hip_runtime.h>
#include <cstdint>
#include <cstddef>

typedef __attribute__((ext_vector_type(8))) short bf16x8;
typedef __attribute__((ext_vector_type(4))) short bf16x4;
typedef __attribute__((ext_vector_type(4))) float f32x4;
typedef __attribute__((ext_vector_type(4))) unsigned int u32x4;
typedef __attribute__((ext_vector_type(2))) unsigned int u32x2;

__device__ inline unsigned short f2b(float f){
  unsigned int u = __float_as_uint(f);
  u += 0x7fffu + ((u >> 16) & 1u);
  return (unsigned short)(u >> 16);
}
// pack two fp32 -> bf16 pair via v_perm (probs >= 0, round-half-up)
__device__ inline unsigned int pk2(float a, float b){
  unsigned int ua = __float_as_uint(a) + 0x8000u;
  unsigned int ub = __float_as_uint(b) + 0x8000u;
  return __builtin_amdgcn_perm(ub, ua, 0x07060302u);
}
// async global->LDS, 16B/lane; LDS dest = wave-uniform base + lane*16
__device__ inline void gl2lds16(const void* g, void* l){
  __builtin_amdgcn_global_load_lds(
      (const __attribute__((address_space(1))) unsigned int*)g,
      (__attribute__((address_space(3))) unsigned int*)l, 16, 0, 0);
}

#define QSCALE 0.18033688011112042f   // 0.125 * log2(e): softmax in log2 domain

// ---------------------------------------------------------------------------
// Weight convert + transpose: Wt[c][k] = W[k][c], fp32 -> bf16.
// ---------------------------------------------------------------------------
__global__ __launch_bounds__(256) void wcvt_kernel(
    const float* __restrict__ Wq, const float* __restrict__ Wkv,
    const float* __restrict__ Wout,
    unsigned short* __restrict__ Wqkv_t, unsigned short* __restrict__ Wout_t)
{
  __shared__ short tile[64*72];
  int cg0 = blockIdx.x * 64;
  int kt  = blockIdx.y * 64;
  const float* src; int ld; int col0; unsigned short* dst; int drow0;
  if (cg0 < 1024)      { src = Wq;   ld = 1024; col0 = cg0;        dst = Wqkv_t; drow0 = cg0; }
  else if (cg0 < 3072) { src = Wkv;  ld = 2048; col0 = cg0 - 1024; dst = Wqkv_t; drow0 = cg0; }
  else                 { src = Wout; ld = 1024; col0 = cg0 - 3072; dst = Wout_t; drow0 = cg0 - 3072; }
  int t = threadIdx.x;
  #pragma unroll
  for (int i = 0; i < 16; ++i){
    int lin = t + 256*i;
    int k = lin >> 6, c = lin & 63;
    tile[k*72 + c] = (short)f2b(src[(size_t)(kt + k)*ld + col0 + c]);
  }
  __syncthreads();
  #pragma unroll
  for (int i = 0; i < 16; ++i){
    int lin = t + 256*i;
    int c = lin >> 6, k = lin & 63;
    dst[(size_t)(drow0 + c)*1024 + kt + k] = (unsigned short)tile[k*72 + c];
  }
}

// ---------------------------------------------------------------------------
// LayerNorm over 1024 cols, one block per row.
// ---------------------------------------------------------------------------
template<bool BF16OUT>
__global__ __launch_bounds__(256) void ln1024_kernel(
    const float* __restrict__ X, const float* __restrict__ G,
    const float* __restrict__ Bb, void* __restrict__ out)
{
  int row = blockIdx.x, t = threadIdx.x;
  float4 x = ((const float4*)(X + (size_t)row*1024))[t];
  float s  = x.x + x.y + x.z + x.w;
  float s2 = x.x*x.x + x.y*x.y + x.z*x.z + x.w*x.w;
  #pragma unroll
  for (int o = 32; o > 0; o >>= 1){ s += __shfl_down(s, o); s2 += __shfl_down(s2, o); }
  __shared__ float red[8];
  int w = t >> 6;
  if ((t & 63) == 0){ red[w] = s; red[4 + w] = s2; }
  __syncthreads();
  float mu  = (red[0]+red[1]+red[2]+red[3]) * (1.0f/1024.0f);
  float var = (red[4]+red[5]+red[6]+red[7]) * (1.0f/1024.0f) - mu*mu;
  float rstd = rsqrtf(var + 1e-5f);
  float4 g = ((const float4*)G)[t];
  float4 b = ((const float4*)Bb)[t];
  float y0 = (x.x-mu)*rstd*g.x + b.x;
  float y1 = (x.y-mu)*rstd*g.y + b.y;
  float y2 = (x.z-mu)*rstd*g.z + b.z;
  float y3 = (x.w-mu)*rstd*g.w + b.w;
  if (BF16OUT){
    ushort4 u; u.x = f2b(y0); u.y = f2b(y1); u.z = f2b(y2); u.w = f2b(y3);
    ((ushort4*)out)[(size_t)row*256 + t] = u;
  } else {
    float4 y; y.x = y0; y.y = y1; y.z = y2; y.w = y3;
    ((float4*)out)[(size_t)row*256 + t] = y;
  }
}

// ---------------------------------------------------------------------------
// Ctx path: kext [b][key][64]; vext transposed [b][64][192].
// Also fills null key (row 0) + zero pad rows 129..191 (blocks 0..127).
// ---------------------------------------------------------------------------
__global__ __launch_bounds__(128) void ctx_kernel(
    const float* __restrict__ Cemb, const float* __restrict__ G,
    const float* __restrict__ Bb, const float* __restrict__ Wctx,
    const float* __restrict__ bctx, const float* __restrict__ nullkv,
    unsigned short* __restrict__ kext, unsigned short* __restrict__ vext_t)
{
  int row = blockIdx.x;            // 0..255  (b*128 + m)
  int b = row >> 7, m = row & 127;
  int t = threadIdx.x;
  // fill duty: blocks 0..127 cover {row0, rows 129..191} x 2 batches
  if (row < 128){
    int b2 = row >> 6, fr = row & 63;
    int frow = (fr == 0) ? 0 : (128 + fr);
    if (t < 64){
      kext[((size_t)b2*192 + frow)*64 + t] = (frow == 0) ? f2b(nullkv[t]) : (unsigned short)0;
    } else {
      int d = t - 64;
      vext_t[((size_t)b2*64 + d)*192 + frow] = (frow == 0) ? f2b(nullkv[64 + d]) : (unsigned short)0;
    }
  }
  const float* xr = Cemb + (size_t)row*768;
  float v[6]; float s = 0.f, s2 = 0.f;
  #pragma unroll
  for (int j = 0; j < 6; ++j){ float xv = xr[t + 128*j]; v[j] = xv; s += xv; s2 += xv*xv; }
  #pragma unroll
  for (int o = 32; o > 0; o >>= 1){ s += __shfl_down(s, o); s2 += __shfl_down(s2, o); }
  __shared__ float red[4];
  __shared__ float xn[768];
  int w = t >> 6;
  if ((t & 63) == 0){ red[w] = s; red[2 + w] = s2; }
  __syncthreads();
  float mu  = (red[0]+red[1]) * (1.0f/768.0f);
  float var = (red[2]+red[3]) * (1.0f/768.0f) - mu*mu;
  float rstd = rsqrtf(var + 1e-5f);
  #pragma unroll
  for (int j = 0; j < 6; ++j){ int c = t + 128*j; xn[c] = (v[j]-mu)*rstd*G[c] + Bb[c]; }
  __syncthreads();
  float acc = bctx[t];
  #pragma unroll 8
  for (int j = 0; j < 768; ++j) acc += xn[j] * Wctx[j*128 + t];
  unsigned short hv = f2b(acc);
  if (t < 64) kext[((size_t)b*192 + 1 + m)*64 + t] = hv;
  else        vext_t[((size_t)b*64 + (t - 64))*192 + 1 + m] = hv;
}

// ---------------------------------------------------------------------------
// bt-GEMM mainloop: BK=64, global_load_lds width-16, XOR-swizzled unpadded
// LDS rows (chunk c -> c ^ (row&7)) => DMA writes AND b128 frag reads are
// bank-balanced (8 accesses/bank = min). 128x128 C-tile, 4 waves 2x2.
// ---------------------------------------------------------------------------
#define GEMM_MAINLOOP(A_, Bt_, tM_, tN_)                                        \
  __shared__ __align__(16) short sA[128*64];                                    \
  __shared__ __align__(16) short sB[128*64];                                    \
  int t = threadIdx.x, w = t >> 6, lane = t & 63;                               \
  int wm = w & 1, wn = w >> 1, lm = lane & 15, q = lane >> 4;                   \
  int grow = lane >> 3;                                                         \
  int gchk = ((lane & 7) ^ grow) << 3;                                          \
  f32x4 acc[4][4] = {};                                                         \
  const unsigned short* Aw = A_ + (size_t)(tM_ + w*32 + grow)*1024 + gchk;      \
  const unsigned short* Bw = Bt_ + (size_t)(tN_ + w*32 + grow)*1024 + gchk;     \
  for (int kk = 0; kk < 1024; kk += 64){                                        \
    __syncthreads();                                                            \
    gl2lds16(Aw + kk,            &sA[(w*32     )*64]);                          \
    gl2lds16(Aw + kk +  8*1024,  &sA[(w*32 +  8)*64]);                          \
    gl2lds16(Aw + kk + 16*1024,  &sA[(w*32 + 16)*64]);                          \
    gl2lds16(Aw + kk + 24*1024,  &sA[(w*32 + 24)*64]);                          \
    gl2lds16(Bw + kk,            &sB[(w*32     )*64]);                          \
    gl2lds16(Bw + kk +  8*1024,  &sB[(w*32 +  8)*64]);                          \
    gl2lds16(Bw + kk + 16*1024,  &sB[(w*32 + 16)*64]);                          \
    gl2lds16(Bw + kk + 24*1024,  &sB[(w*32 + 24)*64]);                          \
    __syncthreads();                                                            \
    bf16x8 af[4][2], bfr[4][2];                                                 \
    _Pragma("unroll")                                                           \
    for (int i = 0; i < 4; ++i){                                                \
      int ra = wm*64 + i*16 + lm, rb = wn*64 + i*16 + lm;                       \
      _Pragma("unroll")                                                         \
      for (int hh = 0; hh < 2; ++hh){                                           \
        int sw = ((hh*4 + q) ^ (lm & 7)) << 3;                                  \
        af[i][hh]  = *(const bf16x8*)(&sA[ra*64 + sw]);                         \
        bfr[i][hh] = *(const bf16x8*)(&sB[rb*64 + sw]);                         \
      }                                                                         \
    }                                                                           \
    _Pragma("unroll")                                                           \
    for (int hh = 0; hh < 2; ++hh)                                              \
      _Pragma("unroll")                                                         \
      for (int i = 0; i < 4; ++i)                                               \
        _Pragma("unroll")                                                       \
        for (int j = 0; j < 4; ++j)                                             \
          acc[i][j] = __builtin_amdgcn_mfma_f32_16x16x32_bf16(af[i][hh], bfr[j][hh], acc[i][j], 0, 0, 0); \
  }

// QKV GEMM (1D grid 768, XCD-swizzled). Q pre-scaled; V stored transposed.
__global__ __launch_bounds__(256) void gemm_qkv_kernel(
    const unsigned short* __restrict__ A, const unsigned short* __restrict__ Bt,
    unsigned short* __restrict__ Qb, unsigned short* __restrict__ Kb,
    unsigned short* __restrict__ VtG)
{
  int id = blockIdx.x;
  int xcd = id & 7, r = id >> 3;          // r in [0,96)
  int tM = ((r & 3)*8 + xcd) * 128;       // same-A blocks share an XCD
  int tN = (r >> 2) * 128;                // [0,24) -> Q/K/V regions
  GEMM_MAINLOOP(A, Bt, tM, tN)
  if (tN < 1024){                 // Q region
    #pragma unroll
    for (int i = 0; i < 4; ++i){
      int R0 = tM + wm*64 + i*16 + q*4;
      int b = R0 >> 11, n = R0 & 2047;
      #pragma unroll
      for (int j = 0; j < 4; ++j){
        int Cg = tN + wn*64 + j*16 + lm;
        int h = Cg >> 6, d = Cg & 63;
        size_t base = ((((size_t)(b*16 + h) << 11) | n) << 6) + d;
        #pragma unroll
        for (int rr = 0; rr < 4; ++rr)
          Qb[base + (size_t)rr*64] = f2b(acc[i][j][rr] * QSCALE);
      }
    }
  } else if (tN < 2048){          // K region
    #pragma unroll
    for (int i = 0; i < 4; ++i){
      int R0 = tM + wm*64 + i*16 + q*4;
      int b = R0 >> 11, n = R0 & 2047;
      #pragma unroll
      for (int j = 0; j < 4; ++j){
        int c2 = tN - 1024 + wn*64 + j*16 + lm;
        int h = c2 >> 6, d = c2 & 63;
        size_t base = ((((size_t)(b*16 + h) << 11) | n) << 6) + d;
        #pragma unroll
        for (int rr = 0; rr < 4; ++rr)
          Kb[base + (size_t)rr*64] = f2b(acc[i][j][rr]);
      }
    }
  } else {                        // V region -> transposed, packed 8B stores
    #pragma unroll
    for (int i = 0; i < 4; ++i){
      int R0 = tM + wm*64 + i*16 + q*4;
      int b = R0 >> 11, n = R0 & 2047;
      #pragma unroll
      for (int j = 0; j < 4; ++j){
        int c2 = tN - 2048 + wn*64 + j*16 + lm;
        int h = c2 >> 6, d = c2 & 63;
        ushort4 u;
        u.x = f2b(acc[i][j][0]); u.y = f2b(acc[i][j][1]);
        u.z = f2b(acc[i][j][2]); u.w = f2b(acc[i][j][3]);
        *(ushort4*)(VtG + ((size_t)(b*16 + h)*64 + d)*2048 + n) = u;
      }
    }
  }
}

// Out-proj GEMM (1D grid 256, XCD-swizzled): C fp32.
__global__ __launch_bounds__(256) void gemm_out_kernel(
    const unsigned short* __restrict__ A, const unsigned short* __restrict__ Bt,
    float* __restrict__ C)
{
  int id = blockIdx.x;
  int xcd = id & 7, r = id >> 3;          // r in [0,32)
  int tM = ((r & 3)*8 + xcd) * 128;
  int tN = (r >> 2) * 128;                // [0,8)
  GEMM_MAINLOOP(A, Bt, tM, tN)
  #pragma unroll
  for (int i = 0; i < 4; ++i){
    int R0 = tM + wm*64 + i*16 + q*4;
    #pragma unroll
    for (int j = 0; j < 4; ++j){
      int Cg = tN + wn*64 + j*16 + lm;
      #pragma unroll
      for (int rr = 0; rr < 4; ++rr)
        C[(size_t)(R0 + rr)*1024 + Cg] = acc[i][j][rr];
    }
  }
}

// ---------------------------------------------------------------------------
// Flash attention, transposed: S^T = K*Q^T, O^T = Vt*P^T. 64 queries/wave
// (K/Vt frag reads amortized 2x vs R3), 2-wave blocks, grid 512.
// No-max softmax, register prefetch, conflict-balanced LDS.
// ---------------------------------------------------------------------------
__global__ __launch_bounds__(128, 2) void attn_kernel(
    const unsigned short* __restrict__ Qb, const unsigned short* __restrict__ Kb,
    const unsigned short* __restrict__ VtG, const unsigned short* __restrict__ kext,
    const unsigned short* __restrict__ vext_t, unsigned short* __restrict__ Ob)
{
  __shared__ __align__(16) short sK[64*72];      // [key][d]
  __shared__ __align__(16) short sVt[64*72];     // [d][key]
  __shared__ __align__(16) short sP[2*64*68];    // per-wave P^T [q][key]
  int id = blockIdx.x;
  int xcd = id & 7, slot = id >> 3;              // 4 bh per XCD for L2 locality
  int bh = xcd*4 + (slot >> 4);
  int qt = slot & 15;
  int b = bh >> 4, h = bh & 15;
  int t = threadIdx.x, w = t >> 6, lane = t & 63;
  int lm = lane & 15, q = lane >> 4;

  const unsigned short* Qbase = Qb + ((size_t)bh*2048 + qt*128 + w*64)*64;
  bf16x8 qf[4][2];
  #pragma unroll
  for (int qq = 0; qq < 4; ++qq){
    qf[qq][0] = *(const bf16x8*)(Qbase + (size_t)(qq*16 + lm)*64 + q*8);
    qf[qq][1] = *(const bf16x8*)(Qbase + (size_t)(qq*16 + lm)*64 + q*8 + 32);
  }

  f32x4 o[4][4] = {};                            // [ds][qq]
  float l_i[4] = {0.f, 0.f, 0.f, 0.f};
  short* pw = &sP[w*64*68];

  // staging: 128 threads, row r0 = t>>1, 32-short half c0
  int r0 = t >> 1, c0 = (t & 1) << 5;
  u32x4 kr[4], vr[4];
  {
    const unsigned short* kp = Kb + ((size_t)bh*2048 + r0)*64 + c0;
    const unsigned short* vp = VtG + ((size_t)bh*64 + r0)*2048 + c0;
    #pragma unroll
    for (int jj = 0; jj < 4; ++jj){
      kr[jj] = *(const u32x4*)(kp + 8*jj);
      vr[jj] = *(const u32x4*)(vp + 8*jj);
    }
  }

  for (int tile = 0; tile < 35; ++tile){
    __syncthreads();
    #pragma unroll
    for (int jj = 0; jj < 4; ++jj){
      *(u32x4*)(&sK[r0*72 + c0 + 8*jj])  = kr[jj];
      *(u32x4*)(&sVt[r0*72 + c0 + 8*jj]) = vr[jj];
    }
    __syncthreads();

    if (tile + 1 < 35){                          // prefetch next tile
      int nt = tile + 1;
      bool ext = nt >= 32;
      int kb = ext ? (nt - 32)*64 : nt*64;
      const unsigned short* kp = ext ? (kext + ((size_t)b*192 + kb + r0)*64 + c0)
                                     : (Kb + ((size_t)bh*2048 + kb + r0)*64 + c0);
      const unsigned short* vp = ext ? (vext_t + ((size_t)b*64 + r0)*192 + kb + c0)
                                     : (VtG + ((size_t)bh*64 + r0)*2048 + kb + c0);
      #pragma unroll
      for (int jj = 0; jj < 4; ++jj){
        kr[jj] = *(const u32x4*)(kp + 8*jj);
        vr[jj] = *(const u32x4*)(vp + 8*jj);
      }
    }

    // K-frags once, reused across 4 q-tiles
    bf16x8 kf[4][2];
    #pragma unroll
    for (int st = 0; st < 4; ++st){
      kf[st][0] = *(const bf16x8*)(&sK[(st*16 + lm)*72 + q*8]);
      kf[st][1] = *(const bf16x8*)(&sK[(st*16 + lm)*72 + q*8 + 32]);
    }

    #pragma unroll
    for (int qq = 0; qq < 4; ++qq){
      f32x4 s[4];
      #pragma unroll
      for (int st = 0; st < 4; ++st){
        f32x4 z = {};
        z = __builtin_amdgcn_mfma_f32_16x16x32_bf16(kf[st][0], qf[qq][0], z, 0, 0, 0);
        s[st] = __builtin_amdgcn_mfma_f32_16x16x32_bf16(kf[st][1], qf[qq][1], z, 0, 0, 0);
      }
      if (tile == 34){                           // keys 128..191: only 128 valid
        #pragma unroll
        for (int st = 0; st < 4; ++st)
          #pragma unroll
          for (int rr = 0; rr < 4; ++rr){
            int key = 128 + st*16 + q*4 + rr;
            if (key >= 129) s[st][rr] = -1e30f;
          }
      }
      float sm = 0.f;
      #pragma unroll
      for (int st = 0; st < 4; ++st)
        #pragma unroll
        for (int rr = 0; rr < 4; ++rr){
          float p = __builtin_amdgcn_exp2f(s[st][rr]);
          s[st][rr] = p; sm += p;
        }
      l_i[qq] += sm;
      #pragma unroll
      for (int st = 0; st < 4; ++st){
        u32x2 pkd;
        pkd[0] = pk2(s[st][0], s[st][1]);
        pkd[1] = pk2(s[st][2], s[st][3]);
        *(u32x2*)(&pw[(qq*16 + lm)*68 + st*16 + q*4]) = pkd;
      }
    }

    // O^T += Vt * P^T  (per-wave LDS region; in-order pipe, no barrier)
    bf16x8 pb[4][2];
    #pragma unroll
    for (int qq = 0; qq < 4; ++qq){
      bf16x4 a0 = *(const bf16x4*)(&pw[(qq*16 + lm)*68 + q*8]);
      bf16x4 a1 = *(const bf16x4*)(&pw[(qq*16 + lm)*68 + q*8 + 4]);
      bf16x4 a2 = *(const bf16x4*)(&pw[(qq*16 + lm)*68 + 32 + q*8]);
      bf16x4 a3 = *(const bf16x4*)(&pw[(qq*16 + lm)*68 + 32 + q*8 + 4]);
      pb[qq][0] = __builtin_shufflevector(a0, a1, 0,1,2,3,4,5,6,7);
      pb[qq][1] = __builtin_shufflevector(a2, a3, 0,1,2,3,4,5,6,7);
    }
    #pragma unroll
    for (int ds = 0; ds < 4; ++ds){
      bf16x8 af0 = *(const bf16x8*)(&sVt[(ds*16 + lm)*72 + q*8]);
      bf16x8 af1 = *(const bf16x8*)(&sVt[(ds*16 + lm)*72 + q*8 + 32]);
      #pragma unroll
      for (int qq = 0; qq < 4; ++qq){
        o[ds][qq] = __builtin_amdgcn_mfma_f32_16x16x32_bf16(af0, pb[qq][0], o[ds][qq], 0, 0, 0);
        o[ds][qq] = __builtin_amdgcn_mfma_f32_16x16x32_bf16(af1, pb[qq][1], o[ds][qq], 0, 0, 0);
      }
    }
  }

  // epilogue: 2 shuffles per q-tile for l, packed 8B stores
  #pragma unroll
  for (int qq = 0; qq < 4; ++qq){
    float l = l_i[qq];
    l += __shfl_xor(l, 16);
    l += __shfl_xor(l, 32);
    float inv = 1.0f / l;
    int n = qt*128 + w*64 + qq*16 + lm;
    size_t base = ((size_t)b*2048 + n)*1024 + h*64 + q*4;
    #pragma unroll
    for (int ds = 0; ds < 4; ++ds){
      ushort4 u;
      u.x = f2b(o[ds][qq][0] * inv); u.y = f2b(o[ds][qq][1] * inv);
      u.z = f2b(o[ds][qq][2] * inv); u.w = f2b(o[ds][qq][3] * inv);
      *(ushort4*)(Ob + base + ds*16) = u;
    }
  }
}

// ---------------------------------------------------------------------------
extern "C" void kernel_launch(void* const* d_in, const int* in_sizes, int n_in,
                              void* d_out, int out_size, void* d_ws, size_t ws_size,
                              hipStream_t stream)
{
  const float* x       = (const float*)d_in[0];
  const float* c_emb   = (const float*)d_in[1];
  const float* ln_g    = (const float*)d_in[2];
  const float* ln_b    = (const float*)d_in[3];
  const float* ctx_g   = (const float*)d_in[4];
  const float* ctx_b   = (const float*)d_in[5];
  const float* W_ctx   = (const float*)d_in[6];
  const float* b_ctx   = (const float*)d_in[7];
  const float* W_q     = (const float*)d_in[8];
  const float* W_kv    = (const float*)d_in[9];
  const float* null_kv = (const float*)d_in[10];
  const float* W_out   = (const float*)d_in[11];
  const float* oln_g   = (const float*)d_in[12];
  const float* oln_b   = (const float*)d_in[13];
  float* out = (float*)d_out;

  char* p = (char*)d_ws;
  unsigned short* xn     = (unsigned short*)p; p += (size_t)4096*1024*2;
  unsigned short* Wqkv_t = (unsigned short*)p; p += (size_t)3072*1024*2;
  unsigned short* Wout_t = (unsigned short*)p; p += (size_t)1024*1024*2;
  unsigned short* Qb     = (unsigned short*)p; p += (size_t)32*2048*64*2;
  unsigned short* Kb     = (unsigned short*)p; p += (size_t)32*2048*64*2;
  unsigned short* VtG    = (unsigned short*)p; p += (size_t)32*64*2048*2;
  unsigned short* kext   = (unsigned short*)p; p += (size_t)2*192*64*2;
  unsigned short* vext_t = (unsigned short*)p; p += (size_t)2*64*192*2;
  unsigned short* aout   = (unsigned short*)p; p += (size_t)4096*1024*2;
  float*          ptmp   = (float*)p;          p += (size_t)4096*1024*4;

  wcvt_kernel<<<dim3(64,16), 256, 0, stream>>>(W_q, W_kv, W_out, Wqkv_t, Wout_t);
  ln1024_kernel<true><<<4096, 256, 0, stream>>>(x, ln_g, ln_b, (void*)xn);
  ctx_kernel<<<256, 128, 0, stream>>>(c_emb, ctx_g, ctx_b, W_ctx, b_ctx, null_kv, kext, vext_t);
  gemm_qkv_kernel<<<768, 256, 0, stream>>>(xn, Wqkv_t, Qb, Kb, VtG);
  attn_kernel<<<512, 128, 0, stream>>>(Qb, Kb, VtG, kext, vext_t, aout);
  gemm_out_kernel<<<256, 256, 0, stream>>>(aout, Wout_t, ptmp);
  ln1024_kernel<false><<<4096, 256, 0, stream>>>(ptmp, oln_g, oln_b, (void*)out);
}

// Round 6
// 273.603 us; speedup vs baseline: 1.0568x; 1.0568x over previous
//
#include <hip/hip_runtime.h>
#include <cstdint>
#include <cstddef>

typedef __attribute__((ext_vector_type(8))) short bf16x8;
typedef __attribute__((ext_vector_type(4))) short bf16x4;
typedef __attribute__((ext_vector_type(4))) float f32x4;
typedef __attribute__((ext_vector_type(4))) unsigned int u32x4;
typedef __attribute__((ext_vector_type(2))) unsigned int u32x2;

__device__ inline unsigned short f2b(float f){
  unsigned int u = __float_as_uint(f);
  u += 0x7fffu + ((u >> 16) & 1u);
  return (unsigned short)(u >> 16);
}
// pack two fp32 -> bf16 pair via v_perm (probs >= 0, round-half-up)
__device__ inline unsigned int pk2(float a, float b){
  unsigned int ua = __float_as_uint(a) + 0x8000u;
  unsigned int ub = __float_as_uint(b) + 0x8000u;
  return __builtin_amdgcn_perm(ub, ua, 0x07060302u);
}
// async global->LDS, 16B/lane; LDS dest = wave-uniform base + lane*16
__device__ inline void gl2lds16(const void* g, void* l){
  __builtin_amdgcn_global_load_lds(
      (const __attribute__((address_space(1))) unsigned int*)g,
      (__attribute__((address_space(3))) unsigned int*)l, 16, 0, 0);
}

#define QSCALE 0.18033688011112042f   // 0.125 * log2(e): softmax in log2 domain

// ---------------------------------------------------------------------------
// Weight convert + transpose: Wt[c][k] = W[k][c], fp32 -> bf16.
// ---------------------------------------------------------------------------
__global__ __launch_bounds__(256) void wcvt_kernel(
    const float* __restrict__ Wq, const float* __restrict__ Wkv,
    const float* __restrict__ Wout,
    unsigned short* __restrict__ Wqkv_t, unsigned short* __restrict__ Wout_t)
{
  __shared__ short tile[64*72];
  int cg0 = blockIdx.x * 64;
  int kt  = blockIdx.y * 64;
  const float* src; int ld; int col0; unsigned short* dst; int drow0;
  if (cg0 < 1024)      { src = Wq;   ld = 1024; col0 = cg0;        dst = Wqkv_t; drow0 = cg0; }
  else if (cg0 < 3072) { src = Wkv;  ld = 2048; col0 = cg0 - 1024; dst = Wqkv_t; drow0 = cg0; }
  else                 { src = Wout; ld = 1024; col0 = cg0 - 3072; dst = Wout_t; drow0 = cg0 - 3072; }
  int t = threadIdx.x;
  #pragma unroll
  for (int i = 0; i < 16; ++i){
    int lin = t + 256*i;
    int k = lin >> 6, c = lin & 63;
    tile[k*72 + c] = (short)f2b(src[(size_t)(kt + k)*ld + col0 + c]);
  }
  __syncthreads();
  #pragma unroll
  for (int i = 0; i < 16; ++i){
    int lin = t + 256*i;
    int c = lin >> 6, k = lin & 63;
    dst[(size_t)(drow0 + c)*1024 + kt + k] = (unsigned short)tile[k*72 + c];
  }
}

// ---------------------------------------------------------------------------
// LayerNorm over 1024 cols, one block per row.
// ---------------------------------------------------------------------------
template<bool BF16OUT>
__global__ __launch_bounds__(256) void ln1024_kernel(
    const float* __restrict__ X, const float* __restrict__ G,
    const float* __restrict__ Bb, void* __restrict__ out)
{
  int row = blockIdx.x, t = threadIdx.x;
  float4 x = ((const float4*)(X + (size_t)row*1024))[t];
  float s  = x.x + x.y + x.z + x.w;
  float s2 = x.x*x.x + x.y*x.y + x.z*x.z + x.w*x.w;
  #pragma unroll
  for (int o = 32; o > 0; o >>= 1){ s += __shfl_down(s, o); s2 += __shfl_down(s2, o); }
  __shared__ float red[8];
  int w = t >> 6;
  if ((t & 63) == 0){ red[w] = s; red[4 + w] = s2; }
  __syncthreads();
  float mu  = (red[0]+red[1]+red[2]+red[3]) * (1.0f/1024.0f);
  float var = (red[4]+red[5]+red[6]+red[7]) * (1.0f/1024.0f) - mu*mu;
  float rstd = rsqrtf(var + 1e-5f);
  float4 g = ((const float4*)G)[t];
  float4 b = ((const float4*)Bb)[t];
  float y0 = (x.x-mu)*rstd*g.x + b.x;
  float y1 = (x.y-mu)*rstd*g.y + b.y;
  float y2 = (x.z-mu)*rstd*g.z + b.z;
  float y3 = (x.w-mu)*rstd*g.w + b.w;
  if (BF16OUT){
    ushort4 u; u.x = f2b(y0); u.y = f2b(y1); u.z = f2b(y2); u.w = f2b(y3);
    ((ushort4*)out)[(size_t)row*256 + t] = u;
  } else {
    float4 y; y.x = y0; y.y = y1; y.z = y2; y.w = y3;
    ((float4*)out)[(size_t)row*256 + t] = y;
  }
}

// ---------------------------------------------------------------------------
// Ctx path: kext [b][key][64]; vext transposed [b][64][192].
// Also fills null key (row 0) + zero pad rows 129..191 (blocks 0..127).
// ---------------------------------------------------------------------------
__global__ __launch_bounds__(128) void ctx_kernel(
    const float* __restrict__ Cemb, const float* __restrict__ G,
    const float* __restrict__ Bb, const float* __restrict__ Wctx,
    const float* __restrict__ bctx, const float* __restrict__ nullkv,
    unsigned short* __restrict__ kext, unsigned short* __restrict__ vext_t)
{
  int row = blockIdx.x;            // 0..255  (b*128 + m)
  int b = row >> 7, m = row & 127;
  int t = threadIdx.x;
  if (row < 128){
    int b2 = row >> 6, fr = row & 63;
    int frow = (fr == 0) ? 0 : (128 + fr);
    if (t < 64){
      kext[((size_t)b2*192 + frow)*64 + t] = (frow == 0) ? f2b(nullkv[t]) : (unsigned short)0;
    } else {
      int d = t - 64;
      vext_t[((size_t)b2*64 + d)*192 + frow] = (frow == 0) ? f2b(nullkv[64 + d]) : (unsigned short)0;
    }
  }
  const float* xr = Cemb + (size_t)row*768;
  float v[6]; float s = 0.f, s2 = 0.f;
  #pragma unroll
  for (int j = 0; j < 6; ++j){ float xv = xr[t + 128*j]; v[j] = xv; s += xv; s2 += xv*xv; }
  #pragma unroll
  for (int o = 32; o > 0; o >>= 1){ s += __shfl_down(s, o); s2 += __shfl_down(s2, o); }
  __shared__ float red[4];
  __shared__ float xn[768];
  int w = t >> 6;
  if ((t & 63) == 0){ red[w] = s; red[2 + w] = s2; }
  __syncthreads();
  float mu  = (red[0]+red[1]) * (1.0f/768.0f);
  float var = (red[2]+red[3]) * (1.0f/768.0f) - mu*mu;
  float rstd = rsqrtf(var + 1e-5f);
  #pragma unroll
  for (int j = 0; j < 6; ++j){ int c = t + 128*j; xn[c] = (v[j]-mu)*rstd*G[c] + Bb[c]; }
  __syncthreads();
  float acc = bctx[t];
  #pragma unroll 8
  for (int j = 0; j < 768; ++j) acc += xn[j] * Wctx[j*128 + t];
  unsigned short hv = f2b(acc);
  if (t < 64) kext[((size_t)b*192 + 1 + m)*64 + t] = hv;
  else        vext_t[((size_t)b*64 + (t - 64))*192 + 1 + m] = hv;
}

// ---------------------------------------------------------------------------
// bt-GEMM mainloop (unchanged from R4).
// ---------------------------------------------------------------------------
#define GEMM_MAINLOOP(A_, Bt_, tM_, tN_)                                        \
  __shared__ __align__(16) short sA[128*64];                                    \
  __shared__ __align__(16) short sB[128*64];                                    \
  int t = threadIdx.x, w = t >> 6, lane = t & 63;                               \
  int wm = w & 1, wn = w >> 1, lm = lane & 15, q = lane >> 4;                   \
  int grow = lane >> 3;                                                         \
  int gchk = ((lane & 7) ^ grow) << 3;                                          \
  f32x4 acc[4][4] = {};                                                         \
  const unsigned short* Aw = A_ + (size_t)(tM_ + w*32 + grow)*1024 + gchk;      \
  const unsigned short* Bw = Bt_ + (size_t)(tN_ + w*32 + grow)*1024 + gchk;     \
  for (int kk = 0; kk < 1024; kk += 64){                                        \
    __syncthreads();                                                            \
    gl2lds16(Aw + kk,            &sA[(w*32     )*64]);                          \
    gl2lds16(Aw + kk +  8*1024,  &sA[(w*32 +  8)*64]);                          \
    gl2lds16(Aw + kk + 16*1024,  &sA[(w*32 + 16)*64]);                          \
    gl2lds16(Aw + kk + 24*1024,  &sA[(w*32 + 24)*64]);                          \
    gl2lds16(Bw + kk,            &sB[(w*32     )*64]);                          \
    gl2lds16(Bw + kk +  8*1024,  &sB[(w*32 +  8)*64]);                          \
    gl2lds16(Bw + kk + 16*1024,  &sB[(w*32 + 16)*64]);                          \
    gl2lds16(Bw + kk + 24*1024,  &sB[(w*32 + 24)*64]);                          \
    __syncthreads();                                                            \
    bf16x8 af[4][2], bfr[4][2];                                                 \
    _Pragma("unroll")                                                           \
    for (int i = 0; i < 4; ++i){                                                \
      int ra = wm*64 + i*16 + lm, rb = wn*64 + i*16 + lm;                       \
      _Pragma("unroll")                                                         \
      for (int hh = 0; hh < 2; ++hh){                                           \
        int sw = ((hh*4 + q) ^ (lm & 7)) << 3;                                  \
        af[i][hh]  = *(const bf16x8*)(&sA[ra*64 + sw]);                         \
        bfr[i][hh] = *(const bf16x8*)(&sB[rb*64 + sw]);                         \
      }                                                                         \
    }                                                                           \
    _Pragma("unroll")                                                           \
    for (int hh = 0; hh < 2; ++hh)                                              \
      _Pragma("unroll")                                                         \
      for (int i = 0; i < 4; ++i)                                               \
        _Pragma("unroll")                                                       \
        for (int j = 0; j < 4; ++j)                                             \
          acc[i][j] = __builtin_amdgcn_mfma_f32_16x16x32_bf16(af[i][hh], bfr[j][hh], acc[i][j], 0, 0, 0); \
  }

// QKV GEMM (1D grid 768, XCD-swizzled). Q pre-scaled; V stored transposed.
__global__ __launch_bounds__(256) void gemm_qkv_kernel(
    const unsigned short* __restrict__ A, const unsigned short* __restrict__ Bt,
    unsigned short* __restrict__ Qb, unsigned short* __restrict__ Kb,
    unsigned short* __restrict__ VtG)
{
  int id = blockIdx.x;
  int xcd = id & 7, r = id >> 3;          // r in [0,96)
  int tM = ((r & 3)*8 + xcd) * 128;       // same-A blocks share an XCD
  int tN = (r >> 2) * 128;                // [0,24) -> Q/K/V regions
  GEMM_MAINLOOP(A, Bt, tM, tN)
  if (tN < 1024){                 // Q region
    #pragma unroll
    for (int i = 0; i < 4; ++i){
      int R0 = tM + wm*64 + i*16 + q*4;
      int b = R0 >> 11, n = R0 & 2047;
      #pragma unroll
      for (int j = 0; j < 4; ++j){
        int Cg = tN + wn*64 + j*16 + lm;
        int h = Cg >> 6, d = Cg & 63;
        size_t base = ((((size_t)(b*16 + h) << 11) | n) << 6) + d;
        #pragma unroll
        for (int rr = 0; rr < 4; ++rr)
          Qb[base + (size_t)rr*64] = f2b(acc[i][j][rr] * QSCALE);
      }
    }
  } else if (tN < 2048){          // K region
    #pragma unroll
    for (int i = 0; i < 4; ++i){
      int R0 = tM + wm*64 + i*16 + q*4;
      int b = R0 >> 11, n = R0 & 2047;
      #pragma unroll
      for (int j = 0; j < 4; ++j){
        int c2 = tN - 1024 + wn*64 + j*16 + lm;
        int h = c2 >> 6, d = c2 & 63;
        size_t base = ((((size_t)(b*16 + h) << 11) | n) << 6) + d;
        #pragma unroll
        for (int rr = 0; rr < 4; ++rr)
          Kb[base + (size_t)rr*64] = f2b(acc[i][j][rr]);
      }
    }
  } else {                        // V region -> transposed, packed 8B stores
    #pragma unroll
    for (int i = 0; i < 4; ++i){
      int R0 = tM + wm*64 + i*16 + q*4;
      int b = R0 >> 11, n = R0 & 2047;
      #pragma unroll
      for (int j = 0; j < 4; ++j){
        int c2 = tN - 2048 + wn*64 + j*16 + lm;
        int h = c2 >> 6, d = c2 & 63;
        ushort4 u;
        u.x = f2b(acc[i][j][0]); u.y = f2b(acc[i][j][1]);
        u.z = f2b(acc[i][j][2]); u.w = f2b(acc[i][j][3]);
        *(ushort4*)(VtG + ((size_t)(b*16 + h)*64 + d)*2048 + n) = u;
      }
    }
  }
}

// Out-proj GEMM (1D grid 256, XCD-swizzled): C fp32.
__global__ __launch_bounds__(256) void gemm_out_kernel(
    const unsigned short* __restrict__ A, const unsigned short* __restrict__ Bt,
    float* __restrict__ C)
{
  int id = blockIdx.x;
  int xcd = id & 7, r = id >> 3;          // r in [0,32)
  int tM = ((r & 3)*8 + xcd) * 128;
  int tN = (r >> 2) * 128;                // [0,8)
  GEMM_MAINLOOP(A, Bt, tM, tN)
  #pragma unroll
  for (int i = 0; i < 4; ++i){
    int R0 = tM + wm*64 + i*16 + q*4;
    #pragma unroll
    for (int j = 0; j < 4; ++j){
      int Cg = tN + wn*64 + j*16 + lm;
      #pragma unroll
      for (int rr = 0; rr < 4; ++rr)
        C[(size_t)(R0 + rr)*1024 + Cg] = acc[i][j][rr];
    }
  }
}

// ---------------------------------------------------------------------------
// Flash attention, transposed + in-block split-K. 256 thr = 4 waves in 2
// pairs: pair 0 = key tiles 0..17, pair 1 = 18..34 (additive no-max softmax
// makes the split exact). Each wave: 64 queries. SINGLE explicit smem block
// with manual carving; merge overlay at offset 0 (<= 36864 B K+Vt region,
// guaranteed contiguous) used only after the final barrier.
//   [0,18432)      K buffers (pair p at p*9216)
//   [18432,36864)  Vt buffers (pair p at 18432 + p*9216)
//   [36864,54272)  P scratch (wave w at 36864 + w*4352)
// ---------------------------------------------------------------------------
__global__ __launch_bounds__(256, 2) void attn_kernel(
    const unsigned short* __restrict__ Qb, const unsigned short* __restrict__ Kb,
    const unsigned short* __restrict__ VtG, const unsigned short* __restrict__ kext,
    const unsigned short* __restrict__ vext_t, unsigned short* __restrict__ Ob)
{
  __shared__ __align__(16) char smem[54272];
  int id = blockIdx.x;
  int xcd = id & 7, slot = id >> 3;              // 4 bh per XCD for L2 locality
  int bh = xcd*4 + (slot >> 4);
  int qt = slot & 15;
  int b = bh >> 4, h = bh & 15;
  int t = threadIdx.x, w = t >> 6, lane = t & 63;
  int p = w >> 1, lw = w & 1;
  int lm = lane & 15, q = lane >> 4;

  short* myK = (short*)(smem + p*9216);
  short* myV = (short*)(smem + 18432 + p*9216);
  short* pw  = (short*)(smem + 36864 + w*4352);

  const unsigned short* Qbase = Qb + ((size_t)bh*2048 + qt*128 + lw*64)*64;
  bf16x8 qf[4][2];
  #pragma unroll
  for (int qq = 0; qq < 4; ++qq){
    qf[qq][0] = *(const bf16x8*)(Qbase + (size_t)(qq*16 + lm)*64 + q*8);
    qf[qq][1] = *(const bf16x8*)(Qbase + (size_t)(qq*16 + lm)*64 + q*8 + 32);
  }

  f32x4 o[4][4] = {};                            // [ds][qq]
  float l_i[4] = {0.f, 0.f, 0.f, 0.f};

  // staging within the pair: 128 threads, row r0, 32-short half c0
  int pt = t & 127;
  int r0 = pt >> 1, c0 = (pt & 1) << 5;
  const int t0 = p ? 18 : 0;
  const int t1 = p ? 35 : 18;

  u32x4 kr[4], vr[4];
  {
    const unsigned short* kp = Kb + ((size_t)bh*2048 + t0*64 + r0)*64 + c0;
    const unsigned short* vp = VtG + ((size_t)bh*64 + r0)*2048 + t0*64 + c0;
    #pragma unroll
    for (int jj = 0; jj < 4; ++jj){
      kr[jj] = *(const u32x4*)(kp + 8*jj);
      vr[jj] = *(const u32x4*)(vp + 8*jj);
    }
  }

  for (int it = 0; it < 18; ++it){
    int tile = t0 + it;
    bool valid = tile < t1;
    __syncthreads();
    if (valid){
      #pragma unroll
      for (int jj = 0; jj < 4; ++jj){
        *(u32x4*)(&myK[r0*72 + c0 + 8*jj]) = kr[jj];
        *(u32x4*)(&myV[r0*72 + c0 + 8*jj]) = vr[jj];
      }
    }
    __syncthreads();

    int nt = tile + 1;
    if (nt < t1){                                // prefetch next tile
      bool ext = nt >= 32;
      int kb = ext ? (nt - 32)*64 : nt*64;
      const unsigned short* kp = ext ? (kext + ((size_t)b*192 + kb + r0)*64 + c0)
                                     : (Kb + ((size_t)bh*2048 + kb + r0)*64 + c0);
      const unsigned short* vp = ext ? (vext_t + ((size_t)b*64 + r0)*192 + kb + c0)
                                     : (VtG + ((size_t)bh*64 + r0)*2048 + kb + c0);
      #pragma unroll
      for (int jj = 0; jj < 4; ++jj){
        kr[jj] = *(const u32x4*)(kp + 8*jj);
        vr[jj] = *(const u32x4*)(vp + 8*jj);
      }
    }
    if (!valid) continue;                        // barriers already passed

    bf16x8 kf[4][2];
    #pragma unroll
    for (int st = 0; st < 4; ++st){
      kf[st][0] = *(const bf16x8*)(&myK[(st*16 + lm)*72 + q*8]);
      kf[st][1] = *(const bf16x8*)(&myK[(st*16 + lm)*72 + q*8 + 32]);
    }

    #pragma unroll
    for (int qp = 0; qp < 2; ++qp){              // qq pairs {0,1},{2,3}
      f32x4 s[2][4];
      #pragma unroll
      for (int qh = 0; qh < 2; ++qh){
        int qq = qp*2 + qh;
        #pragma unroll
        for (int st = 0; st < 4; ++st){
          f32x4 z = {};
          z = __builtin_amdgcn_mfma_f32_16x16x32_bf16(kf[st][0], qf[qq][0], z, 0, 0, 0);
          s[qh][st] = __builtin_amdgcn_mfma_f32_16x16x32_bf16(kf[st][1], qf[qq][1], z, 0, 0, 0);
        }
      }
      if (tile == 34){                           // keys 128..191: only 128 valid
        #pragma unroll
        for (int qh = 0; qh < 2; ++qh)
          #pragma unroll
          for (int st = 0; st < 4; ++st)
            #pragma unroll
            for (int rr = 0; rr < 4; ++rr){
              int key = 128 + st*16 + q*4 + rr;
              if (key >= 129) s[qh][st][rr] = -1e30f;
            }
      }
      #pragma unroll
      for (int qh = 0; qh < 2; ++qh){
        float sm = 0.f;
        #pragma unroll
        for (int st = 0; st < 4; ++st)
          #pragma unroll
          for (int rr = 0; rr < 4; ++rr){
            float pv = __builtin_amdgcn_exp2f(s[qh][st][rr]);
            s[qh][st][rr] = pv; sm += pv;
          }
        l_i[qp*2 + qh] += sm;
        #pragma unroll
        for (int st = 0; st < 4; ++st){
          u32x2 pkd;
          pkd[0] = pk2(s[qh][st][0], s[qh][st][1]);
          pkd[1] = pk2(s[qh][st][2], s[qh][st][3]);
          *(u32x2*)(&pw[(qh*16 + lm)*68 + st*16 + q*4]) = pkd;
        }
      }
      // read back (per-wave region, in-order DS pipe -> no barrier)
      bf16x8 pb[2][2];
      #pragma unroll
      for (int qh = 0; qh < 2; ++qh){
        bf16x4 a0 = *(const bf16x4*)(&pw[(qh*16 + lm)*68 + q*8]);
        bf16x4 a1 = *(const bf16x4*)(&pw[(qh*16 + lm)*68 + q*8 + 4]);
        bf16x4 a2 = *(const bf16x4*)(&pw[(qh*16 + lm)*68 + 32 + q*8]);
        bf16x4 a3 = *(const bf16x4*)(&pw[(qh*16 + lm)*68 + 32 + q*8 + 4]);
        pb[qh][0] = __builtin_shufflevector(a0, a1, 0,1,2,3,4,5,6,7);
        pb[qh][1] = __builtin_shufflevector(a2, a3, 0,1,2,3,4,5,6,7);
      }
      #pragma unroll
      for (int ds = 0; ds < 4; ++ds){
        bf16x8 af0 = *(const bf16x8*)(&myV[(ds*16 + lm)*72 + q*8]);
        bf16x8 af1 = *(const bf16x8*)(&myV[(ds*16 + lm)*72 + q*8 + 32]);
        #pragma unroll
        for (int qh = 0; qh < 2; ++qh){
          int qq = qp*2 + qh;
          o[ds][qq] = __builtin_amdgcn_mfma_f32_16x16x32_bf16(af0, pb[qh][0], o[ds][qq], 0, 0, 0);
          o[ds][qq] = __builtin_amdgcn_mfma_f32_16x16x32_bf16(af1, pb[qh][1], o[ds][qq], 0, 0, 0);
        }
      }
    }
  }

  // ---- merge the two key-halves (additive: no rescale needed) ----
  // overlay at smem offset 0: 2 waves x 64 lanes x 68 floats = 34816 B
  // (fits in the 36864 B K+Vt region of THIS single allocation; K/Vt dead)
  float* mb = (float*)smem;
  float* reg = mb + lw*4352 + lane*68;
  __syncthreads();                               // all KV/P reads done
  if (p == 1){
    #pragma unroll
    for (int ds = 0; ds < 4; ++ds)
      #pragma unroll
      for (int qq = 0; qq < 4; ++qq)
        *(f32x4*)(reg + (ds*4 + qq)*4) = o[ds][qq];
    #pragma unroll
    for (int qq = 0; qq < 4; ++qq) reg[64 + qq] = l_i[qq];
  }
  __syncthreads();
  if (p == 0){
    #pragma unroll
    for (int qq = 0; qq < 4; ++qq){
      #pragma unroll
      for (int ds = 0; ds < 4; ++ds){
        f32x4 ov = *(const f32x4*)(reg + (ds*4 + qq)*4);
        o[ds][qq] += ov;
      }
      float l = l_i[qq] + reg[64 + qq];
      l += __shfl_xor(l, 16);
      l += __shfl_xor(l, 32);
      float inv = 1.0f / l;
      int n = qt*128 + lw*64 + qq*16 + lm;
      size_t base = ((size_t)b*2048 + n)*1024 + h*64 + q*4;
      #pragma unroll
      for (int ds = 0; ds < 4; ++ds){
        ushort4 u;
        u.x = f2b(o[ds][qq][0] * inv); u.y = f2b(o[ds][qq][1] * inv);
        u.z = f2b(o[ds][qq][2] * inv); u.w = f2b(o[ds][qq][3] * inv);
        *(ushort4*)(Ob + base + ds*16) = u;
      }
    }
  }
}

// ---------------------------------------------------------------------------
extern "C" void kernel_launch(void* const* d_in, const int* in_sizes, int n_in,
                              void* d_out, int out_size, void* d_ws, size_t ws_size,
                              hipStream_t stream)
{
  const float* x       = (const float*)d_in[0];
  const float* c_emb   = (const float*)d_in[1];
  const float* ln_g    = (const float*)d_in[2];
  const float* ln_b    = (const float*)d_in[3];
  const float* ctx_g   = (const float*)d_in[4];
  const float* ctx_b   = (const float*)d_in[5];
  const float* W_ctx   = (const float*)d_in[6];
  const float* b_ctx   = (const float*)d_in[7];
  const float* W_q     = (const float*)d_in[8];
  const float* W_kv    = (const float*)d_in[9];
  const float* null_kv = (const float*)d_in[10];
  const float* W_out   = (const float*)d_in[11];
  const float* oln_g   = (const float*)d_in[12];
  const float* oln_b   = (const float*)d_in[13];
  float* out = (float*)d_out;

  char* p = (char*)d_ws;
  unsigned short* xn     = (unsigned short*)p; p += (size_t)4096*1024*2;
  unsigned short* Wqkv_t = (unsigned short*)p; p += (size_t)3072*1024*2;
  unsigned short* Wout_t = (unsigned short*)p; p += (size_t)1024*1024*2;
  unsigned short* Qb     = (unsigned short*)p; p += (size_t)32*2048*64*2;
  unsigned short* Kb     = (unsigned short*)p; p += (size_t)32*2048*64*2;
  unsigned short* VtG    = (unsigned short*)p; p += (size_t)32*64*2048*2;
  unsigned short* kext   = (unsigned short*)p; p += (size_t)2*192*64*2;
  unsigned short* vext_t = (unsigned short*)p; p += (size_t)2*64*192*2;
  unsigned short* aout   = (unsigned short*)p; p += (size_t)4096*1024*2;
  float*          ptmp   = (float*)p;          p += (size_t)4096*1024*4;

  wcvt_kernel<<<dim3(64,16), 256, 0, stream>>>(W_q, W_kv, W_out, Wqkv_t, Wout_t);
  ln1024_kernel<true><<<4096, 256, 0, stream>>>(x, ln_g, ln_b, (void*)xn);
  ctx_kernel<<<256, 128, 0, stream>>>(c_emb, ctx_g, ctx_b, W_ctx, b_ctx, null_kv, kext, vext_t);
  gemm_qkv_kernel<<<768, 256, 0, stream>>>(xn, Wqkv_t, Qb, Kb, VtG);
  attn_kernel<<<512, 256, 0, stream>>>(Qb, Kb, VtG, kext, vext_t, aout);
  gemm_out_kernel<<<256, 256, 0, stream>>>(aout, Wout_t, ptmp);
  ln1024_kernel<false><<<4096, 256, 0, stream>>>(ptmp, oln_g, oln_b, (void*)out);
}